// Round 1
// baseline (270.367 us; speedup 1.0000x reference)
//
#include <hip/hip_runtime.h>
#include <hip/hip_cooperative_groups.h>
#include <math.h>

// Problem constants (B derived at launch; spatial dims fixed by weight shapes).
#define HH 1024
#define WW 1024
#define N1 262144   // 512*512 per-image level-1 detail size
#define N2 65536    // 256*256
#define N3 16384    // 128*128
#define NCHUNK 4           // batch chunks; each block handles B/NCHUNK images
#define ROWS_PER_IMG 512   // fallback-path partial rows per image
#define MAX_IPC 8          // LDS sizing bound for the fused kernel

#define C_INV_SQRT2 0.70710678118654752440f

namespace cg = cooperative_groups;

static __device__ __forceinline__ void haar_fwd(float P, float Q, float R, float S,
                                                float& a, float& h, float& v, float& d) {
    // reference: split along -1 (cols) first, then -2 (rows)
    const float C = C_INV_SQRT2;
    float lo0 = (P + Q) * C, lo1 = (R + S) * C;
    float hi0 = (P - Q) * C, hi1 = (R - S) * C;
    a = (lo0 + lo1) * C; h = (lo0 - lo1) * C;
    v = (hi0 + hi1) * C; d = (hi0 - hi1) * C;
}

static __device__ __forceinline__ void haar_inv(float a, float h, float v, float d,
                                                float& P, float& Q, float& R, float& S) {
    // reference: merge along -2 (rows) first, then -1 (cols)
    // P=(r0,c0) Q=(r0,c1) R=(r1,c0) S=(r1,c1)
    const float C = C_INV_SQRT2;
    float elo = (a + h) * C, olo = (a - h) * C;
    float ehi = (v + d) * C, ohi = (v - d) * C;
    P = (elo + ehi) * C; Q = (elo - ehi) * C;
    R = (olo + ohi) * C; S = (olo - ohi) * C;
}

// ---------------------------------------------------------------------------
// FUSED cooperative kernel: fwd dots -> grid.sync -> gates (redundant per
// block) -> recon. Grid (128 strips, NCHUNK); 256 threads; 2 blocks/CU
// guaranteed co-resident (launch_bounds(256,2) caps VGPR<=256, LDS ~5.4KB).
// Phase-1 compute is the verified wa_fwd_dots body; reduction is cheapened:
// 4-stage xor (16-lane groups) + single predicated LDS write + 40-thread
// tail, replacing the 6-stage/64-lane butterfly (60 -> 40 swizzles/img,
// 10 -> 1 DS writes/img). partial shrinks to [B,128,10] (block-level rows).
// Phase 2 is computed redundantly by every block for its own ipc images
// (5KB L2-hit read each) so only ONE grid.sync is needed and gates never
// round-trip through HBM. Phase 3 is the verified wa_recon body.
// ---------------------------------------------------------------------------
__global__ __launch_bounds__(256, 2) void wa_fused(
    const float* __restrict__ x,
    const float* __restrict__ Wa,
    const float* __restrict__ ba,
    const float* __restrict__ Wd1,   // [3*N3, 3] coarsest
    const float* __restrict__ bd1,
    const float* __restrict__ Wd2,   // [3*N2, 3]
    const float* __restrict__ bd2,
    const float* __restrict__ Wd3,   // [3*N1, 3] finest
    const float* __restrict__ bd3,
    float* __restrict__ partial,     // [B, 128, 10]
    float* __restrict__ out,
    int ipc)                         // images per chunk (= B/NCHUNK)
{
    const int strip = blockIdx.x;          // [0,128): pixel rows strip*8..+8
    const int chunk = blockIdx.y;
    const int t = threadIdx.x;             // L2-col index; px cols 4t..4t+3
    const int lane = t & 63, wave = t >> 6;

    __shared__ float smP[MAX_IPC][16][10]; // per-image 16-group partials
    __shared__ float smG[2][10];           // phase-2 per-wave sums
    __shared__ float gl[10];               // gates for current image

    // ---- strip weights -> registers (once per block, reused ipc times) ----
    float w1[3][4][6];
    #pragma unroll
    for (int qr = 0; qr < 4; ++qr) {
        const size_t jj = (size_t)(strip * 4 + qr) * 512 + 2 * t;
        #pragma unroll
        for (int s = 0; s < 3; ++s) {
            const float2* src = (const float2*)(Wd3 + (jj + (size_t)s * N1) * 3);
            float2 f0 = src[0], f1 = src[1], f2 = src[2];
            w1[s][qr][0] = f0.x; w1[s][qr][1] = f0.y; w1[s][qr][2] = f1.x;
            w1[s][qr][3] = f1.y; w1[s][qr][4] = f2.x; w1[s][qr][5] = f2.y;
        }
    }
    float w2[3][2][3];
    #pragma unroll
    for (int QR = 0; QR < 2; ++QR) {
        const size_t jj = (size_t)(strip * 2 + QR) * 256 + t;
        #pragma unroll
        for (int s = 0; s < 3; ++s) {
            const float* src = Wd2 + (jj + (size_t)s * N2) * 3;
            w2[s][QR][0] = src[0]; w2[s][QR][1] = src[1]; w2[s][QR][2] = src[2];
        }
    }
    float w3[3][3] = {};
    float wa = 0.f;
    if (!(t & 1)) {
        const size_t jj = (size_t)strip * 128 + (t >> 1);
        wa = Wa[jj];
        #pragma unroll
        for (int s = 0; s < 3; ++s) {
            const float* src = Wd1 + (jj + (size_t)s * N3) * 3;
            w3[s][0] = src[0]; w3[s][1] = src[1]; w3[s][2] = src[2];
        }
    }

    // ---- phase 1: forward DWT + logit partials ----
    #pragma unroll 2
    for (int bi = 0; bi < ipc; ++bi) {
        const int b = chunk * ipc + bi;
        const float* xr = x + (size_t)b * HH * WW + (size_t)strip * 8 * WW + 4 * t;

        float acc[10];
        #pragma unroll
        for (int c = 0; c < 10; ++c) acc[c] = 0.f;

        float a1[4][2];
        #pragma unroll
        for (int qr = 0; qr < 4; ++qr) {
            float4 u0 = *(const float4*)(xr + (size_t)(2 * qr)     * WW);
            float4 u1 = *(const float4*)(xr + (size_t)(2 * qr + 1) * WW);
            float h_[2], v_[2], d_[2];
            haar_fwd(u0.x, u0.y, u1.x, u1.y, a1[qr][0], h_[0], v_[0], d_[0]);
            haar_fwd(u0.z, u0.w, u1.z, u1.w, a1[qr][1], h_[1], v_[1], d_[1]);
            #pragma unroll
            for (int qc = 0; qc < 2; ++qc)
                #pragma unroll
                for (int c = 0; c < 3; ++c)
                    acc[7 + c] += h_[qc] * w1[0][qr][qc * 3 + c]
                                + v_[qc] * w1[1][qr][qc * 3 + c]
                                + d_[qc] * w1[2][qr][qc * 3 + c];
        }

        float a2[2];
        #pragma unroll
        for (int QR = 0; QR < 2; ++QR) {
            float h2, v2, d2;
            haar_fwd(a1[2 * QR][0], a1[2 * QR][1], a1[2 * QR + 1][0], a1[2 * QR + 1][1],
                     a2[QR], h2, v2, d2);
            #pragma unroll
            for (int c = 0; c < 3; ++c)
                acc[4 + c] += h2 * w2[0][QR][c] + v2 * w2[1][QR][c] + d2 * w2[2][QR][c];
        }

        {
            float oa0 = __shfl_xor(a2[0], 1);
            float oa1 = __shfl_xor(a2[1], 1);
            if (!(t & 1)) {
                float a3, h3, v3, d3;
                haar_fwd(a2[0], oa0, a2[1], oa1, a3, h3, v3, d3);
                acc[0] += a3 * wa;
                #pragma unroll
                for (int c = 0; c < 3; ++c)
                    acc[1 + c] += h3 * w3[0][c] + v3 * w3[1][c] + d3 * w3[2][c];
            }
        }

        // 4-stage xor reduce: every 16-lane group holds its group sums.
        #pragma unroll
        for (int c = 0; c < 10; ++c) {
            float s = acc[c];
            s += __shfl_xor(s, 1);
            s += __shfl_xor(s, 2);
            s += __shfl_xor(s, 4);
            s += __shfl_xor(s, 8);
            acc[c] = s;
        }
        // Lane (g*16+c), c<10, writes channel c of group g — one DS write.
        // Static-index select (rule: no runtime-indexed register arrays).
        const int sel = lane & 15;
        float vsel = acc[0];
        #pragma unroll
        for (int c = 1; c < 10; ++c) vsel = (sel == c) ? acc[c] : vsel;
        if (sel < 10) smP[bi][(wave << 2) | (lane >> 4)][sel] = vsel;
    }
    __syncthreads();
    // tail: 10*ipc threads fold the 16 groups -> one row per (image,strip)
    if (t < ipc * 10) {
        const int bi = t / 10, c = t - bi * 10;
        float s = 0.f;
        #pragma unroll
        for (int j = 0; j < 16; ++j) s += smP[bi][j][c];
        partial[((size_t)(chunk * ipc + bi) * 128 + strip) * 10 + c] = s;
    }

    __threadfence();               // device-scope release before grid barrier
    cg::this_grid().sync();

    // ---- phase 2+3: gates (redundant per block) + reconstruction ----
    for (int bi = 0; bi < ipc; ++bi) {
        const int b = chunk * ipc + bi;

        if (t < 128) {             // waves 0-1: reduce 128 strip rows
            const float* row = partial + ((size_t)b * 128 + t) * 10;
            float v[10];
            #pragma unroll
            for (int c = 0; c < 10; ++c) v[c] = row[c];
            #pragma unroll
            for (int c = 0; c < 10; ++c) {
                #pragma unroll
                for (int off = 1; off < 64; off <<= 1) v[c] += __shfl_xor(v[c], off);
            }
            if (lane == 0) {
                #pragma unroll
                for (int c = 0; c < 10; ++c) smG[wave][c] = v[c];
            }
        }
        __syncthreads();
        if (t == 0) {
            const float* bds[3] = { bd1, bd2, bd3 };
            float s0 = smG[0][0] + smG[1][0];
            gl[0] = 1.f / (1.f + expf(-(s0 + ba[0])));
            #pragma unroll
            for (int lv = 0; lv < 3; ++lv) {
                float l0 = smG[0][1 + 3 * lv + 0] + smG[1][1 + 3 * lv + 0] + bds[lv][0];
                float l1 = smG[0][1 + 3 * lv + 1] + smG[1][1 + 3 * lv + 1] + bds[lv][1];
                float l2 = smG[0][1 + 3 * lv + 2] + smG[1][1 + 3 * lv + 2] + bds[lv][2];
                float m = fmaxf(l0, fmaxf(l1, l2));
                float e0 = expf(l0 - m), e1 = expf(l1 - m), e2 = expf(l2 - m);
                float inv = 1.f / (e0 + e1 + e2);
                gl[1 + 3 * lv + 0] = e0 * inv;
                gl[1 + 3 * lv + 1] = e1 * inv;
                gl[1 + 3 * lv + 2] = e2 * inv;
            }
        }
        __syncthreads();
        float gv[10];
        #pragma unroll
        for (int c = 0; c < 10; ++c) gv[c] = gl[c];
        // NOTE: no trailing barrier needed — next iteration's smG/gl writes
        // occur only after every thread has passed this iteration's second
        // __syncthreads (i.e. after all gl reads completed).

        // recon (verified wa_recon body)
        const float* xr = x + (size_t)b * HH * WW + (size_t)strip * 8 * WW + 4 * t;
        float a1r[4][2], h1[4][2], v1[4][2], d1[4][2];
        #pragma unroll
        for (int qr = 0; qr < 4; ++qr) {
            float4 u0 = *(const float4*)(xr + (size_t)(2 * qr)     * WW);
            float4 u1 = *(const float4*)(xr + (size_t)(2 * qr + 1) * WW);
            haar_fwd(u0.x, u0.y, u1.x, u1.y, a1r[qr][0], h1[qr][0], v1[qr][0], d1[qr][0]);
            haar_fwd(u0.z, u0.w, u1.z, u1.w, a1r[qr][1], h1[qr][1], v1[qr][1], d1[qr][1]);
        }
        float a2r[2], h2[2], v2[2], d2[2];
        #pragma unroll
        for (int QR = 0; QR < 2; ++QR)
            haar_fwd(a1r[2 * QR][0], a1r[2 * QR][1], a1r[2 * QR + 1][0], a1r[2 * QR + 1][1],
                     a2r[QR], h2[QR], v2[QR], d2[QR]);

        float oa0 = __shfl_xor(a2r[0], 1);
        float oa1 = __shfl_xor(a2r[1], 1);
        const bool rightside = t & 1;
        float a3, h3, v3, d3;
        if (!rightside) haar_fwd(a2r[0], oa0, a2r[1], oa1, a3, h3, v3, d3);
        else            haar_fwd(oa0, a2r[0], oa1, a2r[1], a3, h3, v3, d3);

        a3 *= gv[0];
        float P, Q, R, S;
        haar_inv(a3, h3 * gv[1], v3 * gv[2], d3 * gv[3], P, Q, R, S);
        float r2[2];
        r2[0] = rightside ? Q : P;
        r2[1] = rightside ? S : R;

        float ra1[4][2];
        #pragma unroll
        for (int QR = 0; QR < 2; ++QR) {
            haar_inv(r2[QR], h2[QR] * gv[4], v2[QR] * gv[5], d2[QR] * gv[6], P, Q, R, S);
            ra1[2 * QR][0] = P; ra1[2 * QR][1] = Q;
            ra1[2 * QR + 1][0] = R; ra1[2 * QR + 1][1] = S;
        }

        float* orow = out + (size_t)b * HH * WW + (size_t)strip * 8 * WW + 4 * t;
        #pragma unroll
        for (int qr = 0; qr < 4; ++qr) {
            float4 o0, o1;
            haar_inv(ra1[qr][0], h1[qr][0] * gv[7], v1[qr][0] * gv[8], d1[qr][0] * gv[9],
                     o0.x, o0.y, o1.x, o1.y);
            haar_inv(ra1[qr][1], h1[qr][1] * gv[7], v1[qr][1] * gv[8], d1[qr][1] * gv[9],
                     o0.z, o0.w, o1.z, o1.w);
            *(float4*)(orow + (size_t)(2 * qr)     * WW) = o0;
            *(float4*)(orow + (size_t)(2 * qr + 1) * WW) = o1;
        }
    }
}

// ---------------------------------------------------------------------------
// FALLBACK path (verified 3-kernel pipeline) — used if cooperative launch is
// unavailable or B doesn't chunk.
// ---------------------------------------------------------------------------
__global__ __launch_bounds__(256) void wa_fwd_dots(
    const float* __restrict__ x,
    const float* __restrict__ Wa,
    const float* __restrict__ Wd1,
    const float* __restrict__ Wd2,
    const float* __restrict__ Wd3,
    float* __restrict__ partial,     // [B, ROWS_PER_IMG, 10]
    int ipc)
{
    const int strip = blockIdx.x;
    const int chunk = blockIdx.y;
    const int t = threadIdx.x;
    const int lane = t & 63, wave = t >> 6;

    float w1[3][4][6];
    #pragma unroll
    for (int qr = 0; qr < 4; ++qr) {
        const size_t jj = (size_t)(strip * 4 + qr) * 512 + 2 * t;
        #pragma unroll
        for (int s = 0; s < 3; ++s) {
            const float2* src = (const float2*)(Wd3 + (jj + (size_t)s * N1) * 3);
            float2 f0 = src[0], f1 = src[1], f2 = src[2];
            w1[s][qr][0] = f0.x; w1[s][qr][1] = f0.y; w1[s][qr][2] = f1.x;
            w1[s][qr][3] = f1.y; w1[s][qr][4] = f2.x; w1[s][qr][5] = f2.y;
        }
    }
    float w2[3][2][3];
    #pragma unroll
    for (int QR = 0; QR < 2; ++QR) {
        const size_t jj = (size_t)(strip * 2 + QR) * 256 + t;
        #pragma unroll
        for (int s = 0; s < 3; ++s) {
            const float* src = Wd2 + (jj + (size_t)s * N2) * 3;
            w2[s][QR][0] = src[0]; w2[s][QR][1] = src[1]; w2[s][QR][2] = src[2];
        }
    }
    float w3[3][3] = {};
    float wa = 0.f;
    if (!(t & 1)) {
        const size_t jj = (size_t)strip * 128 + (t >> 1);
        wa = Wa[jj];
        #pragma unroll
        for (int s = 0; s < 3; ++s) {
            const float* src = Wd1 + (jj + (size_t)s * N3) * 3;
            w3[s][0] = src[0]; w3[s][1] = src[1]; w3[s][2] = src[2];
        }
    }

    #pragma unroll 2
    for (int bi = 0; bi < ipc; ++bi) {
        const int b = chunk * ipc + bi;
        const float* xr = x + (size_t)b * HH * WW + (size_t)strip * 8 * WW + 4 * t;

        float acc[10];
        #pragma unroll
        for (int c = 0; c < 10; ++c) acc[c] = 0.f;

        float a1[4][2];
        #pragma unroll
        for (int qr = 0; qr < 4; ++qr) {
            float4 u0 = *(const float4*)(xr + (size_t)(2 * qr)     * WW);
            float4 u1 = *(const float4*)(xr + (size_t)(2 * qr + 1) * WW);
            float h_[2], v_[2], d_[2];
            haar_fwd(u0.x, u0.y, u1.x, u1.y, a1[qr][0], h_[0], v_[0], d_[0]);
            haar_fwd(u0.z, u0.w, u1.z, u1.w, a1[qr][1], h_[1], v_[1], d_[1]);
            #pragma unroll
            for (int qc = 0; qc < 2; ++qc)
                #pragma unroll
                for (int c = 0; c < 3; ++c)
                    acc[7 + c] += h_[qc] * w1[0][qr][qc * 3 + c]
                                + v_[qc] * w1[1][qr][qc * 3 + c]
                                + d_[qc] * w1[2][qr][qc * 3 + c];
        }

        float a2[2];
        #pragma unroll
        for (int QR = 0; QR < 2; ++QR) {
            float h2, v2, d2;
            haar_fwd(a1[2 * QR][0], a1[2 * QR][1], a1[2 * QR + 1][0], a1[2 * QR + 1][1],
                     a2[QR], h2, v2, d2);
            #pragma unroll
            for (int c = 0; c < 3; ++c)
                acc[4 + c] += h2 * w2[0][QR][c] + v2 * w2[1][QR][c] + d2 * w2[2][QR][c];
        }

        {
            float oa0 = __shfl_xor(a2[0], 1);
            float oa1 = __shfl_xor(a2[1], 1);
            if (!(t & 1)) {
                float a3, h3, v3, d3;
                haar_fwd(a2[0], oa0, a2[1], oa1, a3, h3, v3, d3);
                acc[0] += a3 * wa;
                #pragma unroll
                for (int c = 0; c < 3; ++c)
                    acc[1 + c] += h3 * w3[0][c] + v3 * w3[1][c] + d3 * w3[2][c];
            }
        }

        #pragma unroll
        for (int c = 0; c < 10; ++c) {
            float s = acc[c];
            #pragma unroll
            for (int off = 1; off < 64; off <<= 1) s += __shfl_xor(s, off);
            acc[c] = s;
        }
        if (lane == 0) {
            float* row = partial + ((size_t)b * ROWS_PER_IMG + (size_t)strip * 4 + wave) * 10;
            #pragma unroll
            for (int c = 0; c < 10; ++c) row[c] = acc[c];
        }
    }
}

__global__ __launch_bounds__(64) void wa_gates(
    const float* __restrict__ partial,
    const float* __restrict__ ba,
    const float* __restrict__ bd1,
    const float* __restrict__ bd2,
    const float* __restrict__ bd3,
    float* __restrict__ gates)
{
    const int b = blockIdx.x;
    const int l = threadIdx.x;
    float v[10];
    #pragma unroll
    for (int c = 0; c < 10; ++c) v[c] = 0.f;
    for (int r = l; r < ROWS_PER_IMG; r += 64) {
        const float* row = partial + ((size_t)b * ROWS_PER_IMG + r) * 10;
        #pragma unroll
        for (int c = 0; c < 10; ++c) v[c] += row[c];
    }
    #pragma unroll
    for (int c = 0; c < 10; ++c) {
        #pragma unroll
        for (int off = 1; off < 64; off <<= 1) v[c] += __shfl_xor(v[c], off);
    }
    if (l == 0) {
        float* G = gates + b * 10;
        G[0] = 1.f / (1.f + expf(-(v[0] + ba[0])));
        const float* bds[3] = { bd1, bd2, bd3 };
        #pragma unroll
        for (int lv = 0; lv < 3; ++lv) {
            float l0 = v[1 + 3 * lv + 0] + bds[lv][0];
            float l1 = v[1 + 3 * lv + 1] + bds[lv][1];
            float l2 = v[1 + 3 * lv + 2] + bds[lv][2];
            float m = fmaxf(l0, fmaxf(l1, l2));
            float e0 = expf(l0 - m), e1 = expf(l1 - m), e2 = expf(l2 - m);
            float inv = 1.f / (e0 + e1 + e2);
            G[1 + 3 * lv + 0] = e0 * inv;
            G[1 + 3 * lv + 1] = e1 * inv;
            G[1 + 3 * lv + 2] = e2 * inv;
        }
    }
}

__global__ __launch_bounds__(256) void wa_recon(
    const float* __restrict__ x,
    const float* __restrict__ gates,
    float* __restrict__ out)
{
    const int strip = blockIdx.x;
    const int b = blockIdx.y;
    const int t = threadIdx.x;

    __shared__ float g[10];
    if (t < 10) g[t] = gates[b * 10 + t];
    __syncthreads();

    const float* xr = x + (size_t)b * HH * WW + (size_t)strip * 8 * WW + 4 * t;

    float a1[4][2], h1[4][2], v1[4][2], d1[4][2];
    #pragma unroll
    for (int qr = 0; qr < 4; ++qr) {
        float4 u0 = *(const float4*)(xr + (size_t)(2 * qr)     * WW);
        float4 u1 = *(const float4*)(xr + (size_t)(2 * qr + 1) * WW);
        haar_fwd(u0.x, u0.y, u1.x, u1.y, a1[qr][0], h1[qr][0], v1[qr][0], d1[qr][0]);
        haar_fwd(u0.z, u0.w, u1.z, u1.w, a1[qr][1], h1[qr][1], v1[qr][1], d1[qr][1]);
    }
    float a2[2], h2[2], v2[2], d2[2];
    #pragma unroll
    for (int QR = 0; QR < 2; ++QR)
        haar_fwd(a1[2 * QR][0], a1[2 * QR][1], a1[2 * QR + 1][0], a1[2 * QR + 1][1],
                 a2[QR], h2[QR], v2[QR], d2[QR]);

    float oa0 = __shfl_xor(a2[0], 1);
    float oa1 = __shfl_xor(a2[1], 1);
    const bool rightside = t & 1;
    float a3, h3, v3, d3;
    if (!rightside) haar_fwd(a2[0], oa0, a2[1], oa1, a3, h3, v3, d3);
    else            haar_fwd(oa0, a2[0], oa1, a2[1], a3, h3, v3, d3);

    a3 *= g[0];
    float P, Q, R, S;
    haar_inv(a3, h3 * g[1], v3 * g[2], d3 * g[3], P, Q, R, S);
    float r2[2];
    r2[0] = rightside ? Q : P;
    r2[1] = rightside ? S : R;

    float ra1[4][2];
    #pragma unroll
    for (int QR = 0; QR < 2; ++QR) {
        haar_inv(r2[QR], h2[QR] * g[4], v2[QR] * g[5], d2[QR] * g[6], P, Q, R, S);
        ra1[2 * QR][0] = P; ra1[2 * QR][1] = Q;
        ra1[2 * QR + 1][0] = R; ra1[2 * QR + 1][1] = S;
    }

    float* orow = out + (size_t)b * HH * WW + (size_t)strip * 8 * WW + 4 * t;
    #pragma unroll
    for (int qr = 0; qr < 4; ++qr) {
        float4 o0, o1;
        haar_inv(ra1[qr][0], h1[qr][0] * g[7], v1[qr][0] * g[8], d1[qr][0] * g[9],
                 o0.x, o0.y, o1.x, o1.y);
        haar_inv(ra1[qr][1], h1[qr][1] * g[7], v1[qr][1] * g[8], d1[qr][1] * g[9],
                 o0.z, o0.w, o1.z, o1.w);
        *(float4*)(orow + (size_t)(2 * qr)     * WW) = o0;
        *(float4*)(orow + (size_t)(2 * qr + 1) * WW) = o1;
    }
}

extern "C" void kernel_launch(void* const* d_in, const int* in_sizes, int n_in,
                              void* d_out, int out_size, void* d_ws, size_t ws_size,
                              hipStream_t stream) {
    const float* x   = (const float*)d_in[0];
    const float* Wa  = (const float*)d_in[1];
    const float* ba  = (const float*)d_in[2];
    const float* Wd1 = (const float*)d_in[3];
    const float* bd1 = (const float*)d_in[4];
    const float* Wd2 = (const float*)d_in[5];
    const float* bd2 = (const float*)d_in[6];
    const float* Wd3 = (const float*)d_in[7];
    const float* bd3 = (const float*)d_in[8];
    float* out = (float*)d_out;

    const int B = in_sizes[0] / (HH * WW);

    float* partial = (float*)d_ws;                               // fused: [B,128,10]
    float* gates   = partial + (size_t)B * ROWS_PER_IMG * 10;    // fallback only

    if ((B % NCHUNK) == 0 && (B / NCHUNK) <= MAX_IPC) {
        int ipcv = B / NCHUNK;
        const float* xa  = x;   const float* Waa = Wa;  const float* baa = ba;
        const float* w1a = Wd1; const float* b1a = bd1;
        const float* w2a = Wd2; const float* b2a = bd2;
        const float* w3a = Wd3; const float* b3a = bd3;
        float* pa = partial; float* oa = out;
        void* args[] = { &xa, &Waa, &baa, &w1a, &b1a, &w2a, &b2a, &w3a, &b3a,
                         &pa, &oa, &ipcv };
        hipError_t e = hipLaunchCooperativeKernel(wa_fused, dim3(128, NCHUNK),
                                                  dim3(256, 1, 1), args, 0u, stream);
        if (e == hipSuccess) return;
        // cooperative unsupported -> fall through to verified 3-kernel path
    }

    int nchunk = NCHUNK, ipc = B / NCHUNK;
    if (B % NCHUNK) { nchunk = B; ipc = 1; }

    dim3 fgrid(128, nchunk);
    wa_fwd_dots<<<fgrid, 256, 0, stream>>>(x, Wa, Wd1, Wd2, Wd3, partial, ipc);
    wa_gates<<<B, 64, 0, stream>>>(partial, ba, bd1, bd2, bd3, gates);
    dim3 rgrid(128, B);
    wa_recon<<<rgrid, 256, 0, stream>>>(x, gates, out);
}